// Round 1
// baseline (3664.070 us; speedup 1.0000x reference)
//
#include <hip/hip_runtime.h>
#include <math.h>

// Problem constants (from reference)
#define TT 2048
#define BB 512
#define II 11
#define HH 33
#define NL 3
#define OO 18
#define NBATCH 2          // batch elements per block
#define SLOT 36           // padded h-vector stride in floats (144 B, 16B aligned)

// fast sigmoid / tanh via v_exp_f32 + v_rcp_f32 (handles +-inf saturation correctly)
__device__ __forceinline__ float sigm_f(float x) {
    float e = __expf(-x);
    return __builtin_amdgcn_rcpf(1.0f + e);
}
__device__ __forceinline__ float tanh_f(float x) {
    float e = __expf(2.0f * x);                       // inf ok
    return 1.0f - 2.0f * __builtin_amdgcn_rcpf(e + 1.0f);
}

// Persistent layer-pipelined LSTM.
// grid = 256 blocks, block = 256 threads. Block handles NBATCH=2 batch elements.
// Thread tid<198: b = tid/99, r = tid%99, l = r/33, j = r%33  -> computes unit (b,l,j).
// Threads 198..219: x prefetchers (22 = 2 batch * 11 features).
// LDS slots per batch: slot0 = x(t) padded to 33, slot l+1 = h of layer l.
__global__ __launch_bounds__(256, 1) void lstm_pipeline_kernel(
    const float* __restrict__ x,
    const float* __restrict__ Wih0, const float* __restrict__ Whh0,
    const float* __restrict__ bih0, const float* __restrict__ bhh0,
    const float* __restrict__ Wih1, const float* __restrict__ Whh1,
    const float* __restrict__ bih1, const float* __restrict__ bhh1,
    const float* __restrict__ Wih2, const float* __restrict__ Whh2,
    const float* __restrict__ bih2, const float* __restrict__ bhh2,
    float* __restrict__ hidden_out)   // [3, 512, 33]
{
    __shared__ float hl[NBATCH][NL + 1][SLOT];

    const int tid = threadIdx.x;

    // zero LDS (pads stay zero forever)
    for (int i = tid; i < NBATCH * (NL + 1) * SLOT; i += 256)
        ((float*)hl)[i] = 0.0f;

    const int  b    = tid / 99;
    const int  r    = tid % 99;
    const int  l    = r / 33;
    const int  j    = r % 33;
    const bool comp = (tid < 198);
    const int  bg   = blockIdx.x * NBATCH + b;

    // prefetch role
    const int  pr   = tid - 198;
    const bool pref = (pr >= 0) && (pr < 2 * II);
    const int  pb   = pref ? (pr / II) : 0;
    const int  pi   = pref ? (pr % II) : 0;
    const float* xrow = x + ((size_t)(blockIdx.x * NBATCH + pb) * TT) * II + pi;

    // ---- load weights into registers (persistent across all timesteps) ----
    float Wi[4][33], Wh[4][33], bias[4];
    if (comp) {
        const float* Wihp = (l == 0) ? Wih0 : (l == 1) ? Wih1 : Wih2;
        const float* Whhp = (l == 0) ? Whh0 : (l == 1) ? Whh1 : Whh2;
        const float* bip  = (l == 0) ? bih0 : (l == 1) ? bih1 : bih2;
        const float* bhp  = (l == 0) ? bhh0 : (l == 1) ? bhh1 : bhh2;
        const int kin = (l == 0) ? II : HH;
        for (int q = 0; q < 4; ++q) {
            const int g = q * HH + j;
            bias[q] = bip[g] + bhp[g];
            for (int k = 0; k < 33; ++k) {
                Wi[q][k] = (k < kin) ? Wihp[g * kin + k] : 0.0f;
                Wh[q][k] = Whhp[g * HH + k];
            }
        }
    }

    __syncthreads();
    // preload x[t=0]
    if (pref) hl[pb][0][pi] = xrow[0];
    __syncthreads();

    float c = 0.0f;

    for (int s = 0; s < TT + NL - 1; ++s) {
        // issue prefetch of x[t = s+1] early
        float xv = 0.0f;
        const bool pload = pref && (s + 1 < TT);
        if (pload) xv = xrow[(size_t)(s + 1) * II];

        float hnew = 0.0f;
        const bool active = comp && (s >= l) && (s - l < TT);
        if (active) {
            // broadcast-read input vector and own previous h from LDS
            float ha[33], hb[33];
            const float4* h4a = (const float4*)(&hl[b][l][0]);
            const float4* h4b = (const float4*)(&hl[b][l + 1][0]);
            #pragma unroll
            for (int m = 0; m < 8; ++m) {
                float4 v = h4a[m];
                ha[4 * m + 0] = v.x; ha[4 * m + 1] = v.y;
                ha[4 * m + 2] = v.z; ha[4 * m + 3] = v.w;
            }
            ha[32] = hl[b][l][32];
            #pragma unroll
            for (int m = 0; m < 8; ++m) {
                float4 v = h4b[m];
                hb[4 * m + 0] = v.x; hb[4 * m + 1] = v.y;
                hb[4 * m + 2] = v.z; hb[4 * m + 3] = v.w;
            }
            hb[32] = hl[b][l + 1][32];

            float a0 = bias[0], a1 = bias[1], a2 = bias[2], a3 = bias[3];
            #pragma unroll
            for (int k = 0; k < 33; ++k) {
                const float v = ha[k];
                a0 += v * Wi[0][k]; a1 += v * Wi[1][k];
                a2 += v * Wi[2][k]; a3 += v * Wi[3][k];
            }
            #pragma unroll
            for (int k = 0; k < 33; ++k) {
                const float v = hb[k];
                a0 += v * Wh[0][k]; a1 += v * Wh[1][k];
                a2 += v * Wh[2][k]; a3 += v * Wh[3][k];
            }

            const float ig = sigm_f(a0);
            const float fg = sigm_f(a1);
            const float gg = tanh_f(a2);
            const float og = sigm_f(a3);
            c = fg * c + ig * gg;
            hnew = og * tanh_f(c);
        }

        __syncthreads();   // all reads of h done

        if (active) {
            hl[b][l + 1][j] = hnew;
            if (s - l == TT - 1)
                hidden_out[((size_t)l * BB + bg) * HH + j] = hnew;
        }
        if (pload) hl[pb][0][pi] = xv;

        __syncthreads();   // writes visible for next superstep
    }
}

// MLP head: hidden [3*512, 33] -> gelu(hidden@W1^T + b1) [.,72] -> @W2^T + b2 [.,18]
__global__ void mlp_head_kernel(const float* __restrict__ hidden,
                                const float* __restrict__ W1, const float* __restrict__ b1,
                                const float* __restrict__ W2, const float* __restrict__ b2,
                                float* __restrict__ out)
{
    const int row = blockIdx.x * blockDim.x + threadIdx.x;   // 0..1535
    if (row >= NL * BB) return;

    float hv[HH];
    #pragma unroll
    for (int k = 0; k < HH; ++k) hv[k] = hidden[row * HH + k];

    float h1[4 * OO];
    #pragma unroll
    for (int m = 0; m < 4 * OO; ++m) {
        float a = b1[m];
        #pragma unroll
        for (int k = 0; k < HH; ++k) a += hv[k] * W1[m * HH + k];
        // exact gelu: 0.5*x*(1+erf(x/sqrt(2)))
        h1[m] = 0.5f * a * (1.0f + erff(a * 0.70710678118654752f));
    }
    #pragma unroll
    for (int o = 0; o < OO; ++o) {
        float a = b2[o];
        #pragma unroll
        for (int m = 0; m < 4 * OO; ++m) a += h1[m] * W2[o * (4 * OO) + m];
        out[row * OO + o] = a;
    }
}

extern "C" void kernel_launch(void* const* d_in, const int* in_sizes, int n_in,
                              void* d_out, int out_size, void* d_ws, size_t ws_size,
                              hipStream_t stream) {
    const float* x    = (const float*)d_in[0];
    const float* Wih0 = (const float*)d_in[1];
    const float* Whh0 = (const float*)d_in[2];
    const float* bih0 = (const float*)d_in[3];
    const float* bhh0 = (const float*)d_in[4];
    const float* Wih1 = (const float*)d_in[5];
    const float* Whh1 = (const float*)d_in[6];
    const float* bih1 = (const float*)d_in[7];
    const float* bhh1 = (const float*)d_in[8];
    const float* Wih2 = (const float*)d_in[9];
    const float* Whh2 = (const float*)d_in[10];
    const float* bih2 = (const float*)d_in[11];
    const float* bhh2 = (const float*)d_in[12];
    const float* W1   = (const float*)d_in[13];
    const float* b1   = (const float*)d_in[14];
    const float* W2   = (const float*)d_in[15];
    const float* b2   = (const float*)d_in[16];

    float* out    = (float*)d_out;                 // [3,512,18] = 27648 floats
    float* hidden = out + NL * BB * OO;            // [3,512,33] = 50688 floats

    lstm_pipeline_kernel<<<BB / NBATCH, 256, 0, stream>>>(
        x, Wih0, Whh0, bih0, bhh0, Wih1, Whh1, bih1, bhh1,
        Wih2, Whh2, bih2, bhh2, hidden);

    mlp_head_kernel<<<(NL * BB + 255) / 256, 256, 0, stream>>>(
        hidden, W1, b1, W2, b2, out);
}

// Round 2
// 2819.216 us; speedup vs baseline: 1.2997x; 1.2997x over previous
//
#include <hip/hip_runtime.h>
#include <math.h>

// Problem constants (from reference)
#define TT 2048
#define BB 512
#define II 11
#define HH 33
#define NL 3
#define OO 18
#define SLOT 36           // padded vector stride in floats (144 B)

// fast sigmoid / tanh via v_exp_f32 + v_rcp_f32 (saturates correctly at +-inf)
__device__ __forceinline__ float sigm_f(float x) {
    float e = __expf(-x);
    return __builtin_amdgcn_rcpf(1.0f + e);
}
__device__ __forceinline__ float tanh_f(float x) {
    float e = __expf(2.0f * x);
    return 1.0f - 2.0f * __builtin_amdgcn_rcpf(e + 1.0f);
}

// Layer-pipelined LSTM, gate-per-thread.
// grid = 512 blocks (one batch element each), block = 448 threads (7 waves).
//   tid < 396 : u = tid>>2 (unit 0..98), q = tid&3 (gate i/f/g/o).
//               l = u/33, j = u%33. Per-thread: 1 gate row (<=72 weight floats in VGPRs).
//   tid 396..406 : x prefetchers (11 features), 2-deep software pipeline.
// LDS: ping-pong buf[2][4][SLOT]; slot 0 = x(t), slot 1+l = h of layer l.
// One barrier per superstep (read buf[s&1], write buf[(s+1)&1]).
__global__ __launch_bounds__(448, 4) void lstm_pipeline_kernel(
    const float* __restrict__ x,
    const float* __restrict__ Wih0, const float* __restrict__ Whh0,
    const float* __restrict__ bih0, const float* __restrict__ bhh0,
    const float* __restrict__ Wih1, const float* __restrict__ Whh1,
    const float* __restrict__ bih1, const float* __restrict__ bhh1,
    const float* __restrict__ Wih2, const float* __restrict__ Whh2,
    const float* __restrict__ bih2, const float* __restrict__ bhh2,
    float* __restrict__ hidden_out)   // [3, 512, 33]
{
    __shared__ float buf[2][NL + 1][SLOT];

    const int tid = threadIdx.x;
    const int bg  = blockIdx.x;

    // zero LDS (pads stay zero forever; h slots start at 0)
    for (int i = tid; i < 2 * (NL + 1) * SLOT; i += 448)
        ((float*)buf)[i] = 0.0f;

    const bool comp = (tid < 396);
    const int  u    = tid >> 2;          // unit 0..98
    const int  q    = tid & 3;           // gate index: 0=i 1=f 2=g 3=o
    const int  l    = (u < 33) ? 0 : (u < 66) ? 1 : 2;
    const int  j    = u - 33 * l;

    // prefetch role
    const int  pi   = tid - 396;
    const bool pref = (pi >= 0) && (pi < II);
    const float* xrow = x + (size_t)bg * TT * II + (pref ? pi : 0);

    // ---- per-thread gate weights in registers ----
    float wi[SLOT], wh[SLOT];
    float bias = 0.0f;
    #pragma unroll
    for (int k = 0; k < SLOT; ++k) { wi[k] = 0.0f; wh[k] = 0.0f; }

    if (comp) {
        const int g = q * HH + j;
        const float* Whhp = (l == 0) ? Whh0 : (l == 1) ? Whh1 : Whh2;
        const float* bip  = (l == 0) ? bih0 : (l == 1) ? bih1 : bih2;
        const float* bhp  = (l == 0) ? bhh0 : (l == 1) ? bhh1 : bhh2;
        bias = bip[g] + bhp[g];
        #pragma unroll
        for (int k = 0; k < SLOT; ++k)
            wh[k] = (k < HH) ? Whhp[g * HH + k] : 0.0f;
        if (l == 0) {
            #pragma unroll
            for (int k = 0; k < 12; ++k)
                wi[k] = (k < II) ? Wih0[g * II + k] : 0.0f;
        } else {
            const float* Wp = (l == 1) ? Wih1 : Wih2;
            #pragma unroll
            for (int k = 0; k < SLOT; ++k)
                wi[k] = (k < HH) ? Wp[g * HH + k] : 0.0f;
        }
    }

    __syncthreads();
    // x pipeline: buf[0] slot0 <- x[0]; v_next = x[1]; v_next2 = x[2]
    float v_next = 0.0f, v_next2 = 0.0f;
    if (pref) {
        buf[0][0][pi] = xrow[0];
        v_next  = xrow[II];
        v_next2 = xrow[2 * II];
    }
    __syncthreads();

    float c = 0.0f;

    for (int s = 0; s < TT + NL - 1; ++s) {
        const int rp = s & 1;
        const int wp = rp ^ 1;

        // ---- x prefetch: store x[s+1], rotate, issue load of x[s+3] ----
        if (pref) {
            if (s + 1 < TT) buf[wp][0][pi] = v_next;       // vmcnt slack: 2 supersteps
            v_next = v_next2;
            if (s + 3 < TT) v_next2 = xrow[(size_t)(s + 3) * II];
        }

        const bool active = comp && (s >= l) && (s - l < TT);
        float hnew = 0.0f;
        if (active) {
            // gate pre-activation: a = bias + in . wi + h_own . wh
            float a0 = bias, a1 = 0.0f, a2 = 0.0f, a3 = 0.0f;
            const float4* h4 = (const float4*)(&buf[rp][l][0]);
            if (l == 0) {
                #pragma unroll
                for (int m = 0; m < 3; ++m) {
                    float4 v = h4[m];
                    a0 += v.x * wi[4 * m + 0]; a1 += v.y * wi[4 * m + 1];
                    a2 += v.z * wi[4 * m + 2]; a3 += v.w * wi[4 * m + 3];
                }
            } else {
                #pragma unroll
                for (int m = 0; m < 9; ++m) {
                    float4 v = h4[m];
                    a0 += v.x * wi[4 * m + 0]; a1 += v.y * wi[4 * m + 1];
                    a2 += v.z * wi[4 * m + 2]; a3 += v.w * wi[4 * m + 3];
                }
            }
            const float4* o4 = (const float4*)(&buf[rp][l + 1][0]);
            #pragma unroll
            for (int m = 0; m < 9; ++m) {
                float4 v = o4[m];
                a0 += v.x * wh[4 * m + 0]; a1 += v.y * wh[4 * m + 1];
                a2 += v.z * wh[4 * m + 2]; a3 += v.w * wh[4 * m + 3];
            }
            const float a = (a0 + a1) + (a2 + a3);

            // exchange the 4 gate values among the unit's 4 adjacent lanes
            const float p1 = __shfl_xor(a, 1, 64);   // a[q^1]
            const float p2 = __shfl_xor(a, 2, 64);   // a[q^2]
            const float p3 = __shfl_xor(p1, 2, 64);  // a[q^3]
            const bool b0 = (q & 1), b1 = (q & 2);
            const float x0 = b0 ? p1 : a;
            const float x1 = b0 ? a  : p1;
            const float x2 = b0 ? p3 : p2;
            const float x3 = b0 ? p2 : p3;
            const float vi = b1 ? x2 : x0;   // gate i (row block 0)
            const float vf = b1 ? x3 : x1;   // gate f (row block 1)
            const float vg = b1 ? x0 : x2;   // gate g (row block 2)
            const float vo = b1 ? x1 : x3;   // gate o (row block 3)

            const float ig = sigm_f(vi);
            const float fg = sigm_f(vf);
            const float gg = tanh_f(vg);
            const float og = sigm_f(vo);
            c = fg * c + ig * gg;            // redundant but identical across the 4 lanes
            hnew = og * tanh_f(c);

            if (q == 0) {
                buf[wp][l + 1][j] = hnew;
                if (s - l == TT - 1)
                    hidden_out[((size_t)l * BB + bg) * HH + j] = hnew;
            }
        }

        __syncthreads();   // writes to buf[wp] visible; everyone advances together
    }
}

// MLP head: hidden [3*512, 33] -> gelu(hidden@W1^T + b1) [.,72] -> @W2^T + b2 [.,18]
__global__ void mlp_head_kernel(const float* __restrict__ hidden,
                                const float* __restrict__ W1, const float* __restrict__ b1,
                                const float* __restrict__ W2, const float* __restrict__ b2,
                                float* __restrict__ out)
{
    const int row = blockIdx.x * blockDim.x + threadIdx.x;   // 0..1535
    if (row >= NL * BB) return;

    float hv[HH];
    #pragma unroll
    for (int k = 0; k < HH; ++k) hv[k] = hidden[row * HH + k];

    float h1[4 * OO];
    #pragma unroll
    for (int m = 0; m < 4 * OO; ++m) {
        float a = b1[m];
        #pragma unroll
        for (int k = 0; k < HH; ++k) a += hv[k] * W1[m * HH + k];
        h1[m] = 0.5f * a * (1.0f + erff(a * 0.70710678118654752f));
    }
    #pragma unroll
    for (int o = 0; o < OO; ++o) {
        float a = b2[o];
        #pragma unroll
        for (int m = 0; m < 4 * OO; ++m) a += h1[m] * W2[o * (4 * OO) + m];
        out[row * OO + o] = a;
    }
}

extern "C" void kernel_launch(void* const* d_in, const int* in_sizes, int n_in,
                              void* d_out, int out_size, void* d_ws, size_t ws_size,
                              hipStream_t stream) {
    const float* x    = (const float*)d_in[0];
    const float* Wih0 = (const float*)d_in[1];
    const float* Whh0 = (const float*)d_in[2];
    const float* bih0 = (const float*)d_in[3];
    const float* bhh0 = (const float*)d_in[4];
    const float* Wih1 = (const float*)d_in[5];
    const float* Whh1 = (const float*)d_in[6];
    const float* bih1 = (const float*)d_in[7];
    const float* bhh1 = (const float*)d_in[8];
    const float* Wih2 = (const float*)d_in[9];
    const float* Whh2 = (const float*)d_in[10];
    const float* bih2 = (const float*)d_in[11];
    const float* bhh2 = (const float*)d_in[12];
    const float* W1   = (const float*)d_in[13];
    const float* b1   = (const float*)d_in[14];
    const float* W2   = (const float*)d_in[15];
    const float* b2   = (const float*)d_in[16];

    float* out    = (float*)d_out;                 // [3,512,18] = 27648 floats
    float* hidden = out + NL * BB * OO;            // [3,512,33] = 50688 floats

    lstm_pipeline_kernel<<<BB, 448, 0, stream>>>(
        x, Wih0, Whh0, bih0, bhh0, Wih1, Whh1, bih1, bhh1,
        Wih2, Whh2, bih2, bhh2, hidden);

    mlp_head_kernel<<<(NL * BB + 255) / 256, 256, 0, stream>>>(
        hidden, W1, b1, W2, b2, out);
}

// Round 3
// 2201.881 us; speedup vs baseline: 1.6641x; 1.2804x over previous
//
#include <hip/hip_runtime.h>
#include <math.h>

// Problem constants (from reference)
#define TT 2048
#define BB 512
#define II 11
#define HH 33
#define NL 3
#define OO 18
#define SLOT 36           // padded vector stride in floats (144 B)

typedef float f2 __attribute__((ext_vector_type(2)));
typedef float f4 __attribute__((ext_vector_type(4)));

// fast sigmoid / tanh via v_exp_f32 + v_rcp_f32 (saturates correctly at +-inf)
__device__ __forceinline__ float sigm_f(float x) {
    float e = __expf(-x);
    return __builtin_amdgcn_rcpf(1.0f + e);
}
__device__ __forceinline__ float tanh_f(float x) {
    float e = __expf(2.0f * x);
    return 1.0f - 2.0f * __builtin_amdgcn_rcpf(e + 1.0f);
}

// load 4 consecutive floats (row not 16B-aligned -> scalar gather, one-time cost)
__device__ __forceinline__ f4 ld4(const float* p) {
    f4 v; v.x = p[0]; v.y = p[1]; v.z = p[2]; v.w = p[3]; return v;
}

// accumulate v . w into two f2 chains (backend emits v_pk_fma_f32)
#define DOT4(V, W) do { f4 _v = (V); s0 += _v.xy * (W).xy; s1 += _v.zw * (W).zw; } while (0)

// Layer-pipelined LSTM, gate-per-thread, weights in NAMED vector registers.
// grid = 512 blocks (one batch element each), block = 448 threads (7 waves).
//   tid < 396 : u = tid>>2 (unit 0..98), q = tid&3 (gate i/f/g/o).
//               l = u/33, j = u%33. Per-thread: 1 gate row in 18 named f4 regs.
//   tid 396..406 : x prefetchers (11 features), 2-deep software pipeline.
// LDS: ping-pong buf[2][4][SLOT]; slot 0 = x(t), slot 1+l = h of layer l.
// One barrier per superstep (read buf[s&1], write buf[(s+1)&1]).
__global__ __launch_bounds__(448, 4) void lstm_pipeline_kernel(
    const float* __restrict__ x,
    const float* __restrict__ Wih0, const float* __restrict__ Whh0,
    const float* __restrict__ bih0, const float* __restrict__ bhh0,
    const float* __restrict__ Wih1, const float* __restrict__ Whh1,
    const float* __restrict__ bih1, const float* __restrict__ bhh1,
    const float* __restrict__ Wih2, const float* __restrict__ Whh2,
    const float* __restrict__ bih2, const float* __restrict__ bhh2,
    float* __restrict__ hidden_out)   // [3, 512, 33]
{
    __shared__ float buf[2][NL + 1][SLOT];

    const int tid = threadIdx.x;
    const int bg  = blockIdx.x;

    for (int i = tid; i < 2 * (NL + 1) * SLOT; i += 448)
        ((float*)buf)[i] = 0.0f;

    const bool comp = (tid < 396);
    const int  u    = tid >> 2;          // unit 0..98
    const int  q    = tid & 3;           // gate index: 0=i 1=f 2=g 3=o
    const int  l    = (u < 33) ? 0 : (u < 66) ? 1 : 2;
    const int  j    = u - 33 * l;

    const int  pi   = tid - 396;
    const bool pref = (pi >= 0) && (pi < II);
    const float* xrow = x + (size_t)bg * TT * II + (pref ? pi : 0);

    // ---- per-thread gate-row weights in NAMED vector registers ----
    f4 wi0 = {0,0,0,0}, wi1 = wi0, wi2 = wi0, wi3 = wi0, wi4 = wi0,
       wi5 = wi0, wi6 = wi0, wi7 = wi0, wi8 = wi0;
    f4 wh0 = wi0, wh1 = wi0, wh2 = wi0, wh3 = wi0, wh4 = wi0,
       wh5 = wi0, wh6 = wi0, wh7 = wi0, wh8 = wi0;
    float bias = 0.0f;

    if (comp) {
        const int g = q * HH + j;
        const float* Whhp = (l == 0) ? Whh0 : (l == 1) ? Whh1 : Whh2;
        const float* bip  = (l == 0) ? bih0 : (l == 1) ? bih1 : bih2;
        const float* bhp  = (l == 0) ? bhh0 : (l == 1) ? bhh1 : bhh2;
        bias = bip[g] + bhp[g];
        const float* hr = Whhp + g * HH;
        wh0 = ld4(hr);      wh1 = ld4(hr + 4);  wh2 = ld4(hr + 8);
        wh3 = ld4(hr + 12); wh4 = ld4(hr + 16); wh5 = ld4(hr + 20);
        wh6 = ld4(hr + 24); wh7 = ld4(hr + 28);
        wh8.x = hr[32];
        if (l == 0) {
            const float* ir = Wih0 + g * II;
            wi0 = ld4(ir); wi1 = ld4(ir + 4);
            wi2.x = ir[8]; wi2.y = ir[9]; wi2.z = ir[10];
        } else {
            const float* ir = ((l == 1) ? Wih1 : Wih2) + g * HH;
            wi0 = ld4(ir);      wi1 = ld4(ir + 4);  wi2 = ld4(ir + 8);
            wi3 = ld4(ir + 12); wi4 = ld4(ir + 16); wi5 = ld4(ir + 20);
            wi6 = ld4(ir + 24); wi7 = ld4(ir + 28);
            wi8.x = ir[32];
        }
    }

    __syncthreads();
    float v_next = 0.0f, v_next2 = 0.0f;
    if (pref) {
        buf[0][0][pi] = xrow[0];
        v_next  = xrow[II];
        v_next2 = xrow[2 * II];
    }
    __syncthreads();

    float c = 0.0f;

    for (int s = 0; s < TT + NL - 1; ++s) {
        const int rp = s & 1;
        const int wp = rp ^ 1;

        if (pref) {
            if (s + 1 < TT) buf[wp][0][pi] = v_next;     // vmcnt slack: 2 supersteps
            v_next = v_next2;
            if (s + 3 < TT) v_next2 = xrow[(size_t)(s + 3) * II];
        }

        const bool active = comp && (s >= l) && (s - l < TT);
        if (active) {
            const f4* A4 = (const f4*)(&buf[rp][l][0]);       // input vector
            const f4* B4 = (const f4*)(&buf[rp][l + 1][0]);   // own previous h

            f2 s0 = {bias, 0.0f}, s1 = {0.0f, 0.0f};
            if (l == 0) {
                DOT4(A4[0], wi0); DOT4(A4[1], wi1); DOT4(A4[2], wi2);
            } else {
                DOT4(A4[0], wi0); DOT4(A4[1], wi1); DOT4(A4[2], wi2);
                DOT4(A4[3], wi3); DOT4(A4[4], wi4); DOT4(A4[5], wi5);
                DOT4(A4[6], wi6); DOT4(A4[7], wi7); DOT4(A4[8], wi8);
            }
            DOT4(B4[0], wh0); DOT4(B4[1], wh1); DOT4(B4[2], wh2);
            DOT4(B4[3], wh3); DOT4(B4[4], wh4); DOT4(B4[5], wh5);
            DOT4(B4[6], wh6); DOT4(B4[7], wh7); DOT4(B4[8], wh8);
            const float a = (s0.x + s0.y) + (s1.x + s1.y);

            // exchange the 4 gate values among the unit's 4 adjacent lanes
            const float p1 = __shfl_xor(a, 1, 64);   // a[q^1]
            const float p2 = __shfl_xor(a, 2, 64);   // a[q^2]
            const float p3 = __shfl_xor(p1, 2, 64);  // a[q^3]
            const bool b0 = (q & 1), b1 = (q & 2);
            const float x0 = b0 ? p1 : a;
            const float x1 = b0 ? a  : p1;
            const float x2 = b0 ? p3 : p2;
            const float x3 = b0 ? p2 : p3;
            const float vi = b1 ? x2 : x0;   // gate i
            const float vf = b1 ? x3 : x1;   // gate f
            const float vg = b1 ? x0 : x2;   // gate g
            const float vo = b1 ? x1 : x3;   // gate o

            const float ig = sigm_f(vi);
            const float fg = sigm_f(vf);
            const float gg = tanh_f(vg);
            const float og = sigm_f(vo);
            c = fg * c + ig * gg;            // identical across the 4 lanes
            const float hnew = og * tanh_f(c);

            if (q == 0) {
                buf[wp][l + 1][j] = hnew;
                if (s - l == TT - 1)
                    hidden_out[((size_t)l * BB + bg) * HH + j] = hnew;
            }
        }

        __syncthreads();
    }
}

// MLP head: hidden [3*512, 33] -> gelu(hidden@W1^T + b1) [.,72] -> @W2^T + b2 [.,18]
__global__ void mlp_head_kernel(const float* __restrict__ hidden,
                                const float* __restrict__ W1, const float* __restrict__ b1,
                                const float* __restrict__ W2, const float* __restrict__ b2,
                                float* __restrict__ out)
{
    const int row = blockIdx.x * blockDim.x + threadIdx.x;   // 0..1535
    if (row >= NL * BB) return;

    float hv[HH];
    #pragma unroll
    for (int k = 0; k < HH; ++k) hv[k] = hidden[row * HH + k];

    float h1[4 * OO];
    #pragma unroll
    for (int m = 0; m < 4 * OO; ++m) {
        float a = b1[m];
        #pragma unroll
        for (int k = 0; k < HH; ++k) a += hv[k] * W1[m * HH + k];
        h1[m] = 0.5f * a * (1.0f + erff(a * 0.70710678118654752f));
    }
    #pragma unroll
    for (int o = 0; o < OO; ++o) {
        float a = b2[o];
        #pragma unroll
        for (int m = 0; m < 4 * OO; ++m) a += h1[m] * W2[o * (4 * OO) + m];
        out[row * OO + o] = a;
    }
}

extern "C" void kernel_launch(void* const* d_in, const int* in_sizes, int n_in,
                              void* d_out, int out_size, void* d_ws, size_t ws_size,
                              hipStream_t stream) {
    const float* x    = (const float*)d_in[0];
    const float* Wih0 = (const float*)d_in[1];
    const float* Whh0 = (const float*)d_in[2];
    const float* bih0 = (const float*)d_in[3];
    const float* bhh0 = (const float*)d_in[4];
    const float* Wih1 = (const float*)d_in[5];
    const float* Whh1 = (const float*)d_in[6];
    const float* bih1 = (const float*)d_in[7];
    const float* bhh1 = (const float*)d_in[8];
    const float* Wih2 = (const float*)d_in[9];
    const float* Whh2 = (const float*)d_in[10];
    const float* bih2 = (const float*)d_in[11];
    const float* bhh2 = (const float*)d_in[12];
    const float* W1   = (const float*)d_in[13];
    const float* b1   = (const float*)d_in[14];
    const float* W2   = (const float*)d_in[15];
    const float* b2   = (const float*)d_in[16];

    float* out    = (float*)d_out;                 // [3,512,18] = 27648 floats
    float* hidden = out + NL * BB * OO;            // [3,512,33] = 50688 floats

    lstm_pipeline_kernel<<<BB, 448, 0, stream>>>(
        x, Wih0, Whh0, bih0, bhh0, Wih1, Whh1, bih1, bhh1,
        Wih2, Whh2, bih2, bhh2, hidden);

    mlp_head_kernel<<<(NL * BB + 255) / 256, 256, 0, stream>>>(
        hidden, W1, b1, W2, b2, out);
}

// Round 4
// 1915.527 us; speedup vs baseline: 1.9128x; 1.1495x over previous
//
#include <hip/hip_runtime.h>
#include <math.h>

// Problem constants (from reference)
#define TT 2048
#define BB 512
#define II 11
#define HH 33
#define NL 3
#define OO 18
#define SLOT 36           // padded vector stride in floats (144 B, 16B-aligned slots)

typedef float f2 __attribute__((ext_vector_type(2)));
typedef float f4 __attribute__((ext_vector_type(4)));

// fast sigmoid / tanh via v_exp_f32 + v_rcp_f32 (saturates correctly at +-inf)
__device__ __forceinline__ float sigm_f(float x) {
    float e = __expf(-x);
    return __builtin_amdgcn_rcpf(1.0f + e);
}
__device__ __forceinline__ float tanh_f(float x) {
    float e = __expf(2.0f * x);
    return 1.0f - 2.0f * __builtin_amdgcn_rcpf(e + 1.0f);
}

// DPP quad_perm lane exchange (VALU pipe, no LDS): xor1 = [1,0,3,2] = 0xB1,
// xor2 = [2,3,0,1] = 0x4E. All 4 lanes of a quad are uniformly active here.
__device__ __forceinline__ float dpp_xor1(float v) {
    return __builtin_bit_cast(float,
        __builtin_amdgcn_update_dpp(0, __builtin_bit_cast(int, v), 0xB1, 0xF, 0xF, true));
}
__device__ __forceinline__ float dpp_xor2(float v) {
    return __builtin_bit_cast(float,
        __builtin_amdgcn_update_dpp(0, __builtin_bit_cast(int, v), 0x4E, 0xF, 0xF, true));
}

// guarded 4-float load: element k0+i valid iff k0+i < rem
__device__ __forceinline__ f4 gld4(const float* p, int k0, int rem) {
    f4 v;
    v.x = (k0 + 0 < rem) ? p[k0 + 0] : 0.0f;
    v.y = (k0 + 1 < rem) ? p[k0 + 1] : 0.0f;
    v.z = (k0 + 2 < rem) ? p[k0 + 2] : 0.0f;
    v.w = (k0 + 3 < rem) ? p[k0 + 3] : 0.0f;
    return v;
}

// Layer-pipelined LSTM, COLUMN-SPLIT quads.
// grid = 512 blocks (one batch element each), block = 448 threads (7 waves).
//   tid < 396 : u = tid>>2 (unit 0..98), q = tid&3 (column-quarter).
//               l = u/33, j = u%33.
//   Lane q reads a 16-col slice of the concatenated (input, own-h) vector:
//     q0: in[0:16), q1: in[16:32) (+in[32]), q2: h[0:16), q3: h[16:32) (+h[32])
//   and accumulates partials of ALL 4 gate rows over that slice.
//   Quad all-reduce via DPP quad_perm -> every lane holds all 4 gate sums.
//   tid 396..406 : x prefetchers (11 features), 2-deep software pipeline.
// LDS: ping-pong buf[2][4][SLOT]; slot 0 = x(t), slot 1+l = h of layer l.
__global__ __launch_bounds__(448, 4) void lstm_pipeline_kernel(
    const float* __restrict__ x,
    const float* __restrict__ Wih0, const float* __restrict__ Whh0,
    const float* __restrict__ bih0, const float* __restrict__ bhh0,
    const float* __restrict__ Wih1, const float* __restrict__ Whh1,
    const float* __restrict__ bih1, const float* __restrict__ bhh1,
    const float* __restrict__ Wih2, const float* __restrict__ Whh2,
    const float* __restrict__ bih2, const float* __restrict__ bhh2,
    float* __restrict__ hidden_out)   // [3, 512, 33]
{
    __shared__ __align__(16) float buf[2][NL + 1][SLOT];

    const int tid = threadIdx.x;
    const int bg  = blockIdx.x;

    for (int i = tid; i < 2 * (NL + 1) * SLOT; i += 448)
        ((float*)buf)[i] = 0.0f;

    const bool comp = (tid < 396);
    const int  u    = tid >> 2;          // unit 0..98
    const int  q    = tid & 3;           // column-quarter
    const int  l    = (u < 33) ? 0 : (u < 66) ? 1 : 2;
    const int  j    = u - 33 * l;

    const int  pi   = tid - 396;
    const bool pref = (pi >= 0) && (pi < II);
    const float* xrow = x + (size_t)bg * TT * II + (pref ? pi : 0);

    // ---- per-lane weights: 4 gate rows x 16-col slice (+1 extra col on odd q) ----
    f4 w0a = {0,0,0,0}, w0b = w0a, w0c = w0a, w0d = w0a;   // gate 0 (i)
    f4 w1a = w0a, w1b = w0a, w1c = w0a, w1d = w0a;         // gate 1 (f)
    f4 w2a = w0a, w2b = w0a, w2c = w0a, w2d = w0a;         // gate 2 (g)
    f4 w3a = w0a, w3b = w0a, w3c = w0a, w3d = w0a;         // gate 3 (o)
    float we0 = 0.0f, we1 = 0.0f, we2 = 0.0f, we3 = 0.0f;  // col-32 weights (odd q)
    float b0 = 0.0f, b1 = 0.0f, b2 = 0.0f, b3 = 0.0f;

    if (comp) {
        const float* bip = (l == 0) ? bih0 : (l == 1) ? bih1 : bih2;
        const float* bhp = (l == 0) ? bhh0 : (l == 1) ? bhh1 : bhh2;
        b0 = bip[0 * HH + j] + bhp[0 * HH + j];
        b1 = bip[1 * HH + j] + bhp[1 * HH + j];
        b2 = bip[2 * HH + j] + bhp[2 * HH + j];
        b3 = bip[3 * HH + j] + bhp[3 * HH + j];

        const float* Wsrc;
        int kin, cbase;
        if (q < 2) {   // slice of W_ih
            kin   = (l == 0) ? II : HH;
            Wsrc  = (l == 0) ? Wih0 : (l == 1) ? Wih1 : Wih2;
            cbase = 16 * q;
        } else {       // slice of W_hh
            kin   = HH;
            Wsrc  = (l == 0) ? Whh0 : (l == 1) ? Whh1 : Whh2;
            cbase = 16 * (q - 2);
        }
        const int rem = kin - cbase;   // valid cols in this slice (may be <=0)
        const float* r0 = Wsrc + (0 * HH + j) * kin + cbase;
        const float* r1 = Wsrc + (1 * HH + j) * kin + cbase;
        const float* r2 = Wsrc + (2 * HH + j) * kin + cbase;
        const float* r3 = Wsrc + (3 * HH + j) * kin + cbase;
        w0a = gld4(r0, 0, rem); w0b = gld4(r0, 4, rem); w0c = gld4(r0, 8, rem); w0d = gld4(r0, 12, rem);
        w1a = gld4(r1, 0, rem); w1b = gld4(r1, 4, rem); w1c = gld4(r1, 8, rem); w1d = gld4(r1, 12, rem);
        w2a = gld4(r2, 0, rem); w2b = gld4(r2, 4, rem); w2c = gld4(r2, 8, rem); w2d = gld4(r2, 12, rem);
        w3a = gld4(r3, 0, rem); w3b = gld4(r3, 4, rem); w3c = gld4(r3, 8, rem); w3d = gld4(r3, 12, rem);
        if ((q & 1) && kin > 32) {   // col 32 assigned to the odd lane of each pair
            we0 = Wsrc[(0 * HH + j) * kin + 32];
            we1 = Wsrc[(1 * HH + j) * kin + 32];
            we2 = Wsrc[(2 * HH + j) * kin + 32];
            we3 = Wsrc[(3 * HH + j) * kin + 32];
        }
    }

    __syncthreads();
    float v_next = 0.0f, v_next2 = 0.0f;
    if (pref) {
        buf[0][0][pi] = xrow[0];
        v_next  = xrow[II];
        v_next2 = xrow[2 * II];
    }
    __syncthreads();

    float c = 0.0f;
    const int vsel = (q < 2) ? l : (l + 1);   // which LDS vector this lane reads

    for (int s = 0; s < TT + NL - 1; ++s) {
        const int rp = s & 1;
        const int wp = rp ^ 1;

        if (pref) {
            if (s + 1 < TT) buf[wp][0][pi] = v_next;     // vmcnt slack: 2 supersteps
            v_next = v_next2;
            if (s + 3 < TT) v_next2 = xrow[(size_t)(s + 3) * II];
        }

        const bool active = comp && (s >= l) && (s - l < TT);
        if (active) {
            // this lane's 16-float slice (4 x ds_read_b128, 4 distinct addrs/wave)
            const f4* V = (const f4*)(&buf[rp][vsel][(q & 1) * 16]);
            const f4 v0 = V[0], v1 = V[1], v2 = V[2], v3 = V[3];
            const float vex = buf[rp][vsel][32];         // col 32 (broadcast b32)

            // partials of all 4 gate rows over this slice (32 pk_fma)
            f2 a0 = {0.0f, 0.0f}, a1 = a0, a2 = a0, a3 = a0;
            a0 += v0.xy * w0a.xy; a0 += v0.zw * w0a.zw;
            a1 += v0.xy * w1a.xy; a1 += v0.zw * w1a.zw;
            a2 += v0.xy * w2a.xy; a2 += v0.zw * w2a.zw;
            a3 += v0.xy * w3a.xy; a3 += v0.zw * w3a.zw;
            a0 += v1.xy * w0b.xy; a0 += v1.zw * w0b.zw;
            a1 += v1.xy * w1b.xy; a1 += v1.zw * w1b.zw;
            a2 += v1.xy * w2b.xy; a2 += v1.zw * w2b.zw;
            a3 += v1.xy * w3b.xy; a3 += v1.zw * w3b.zw;
            a0 += v2.xy * w0c.xy; a0 += v2.zw * w0c.zw;
            a1 += v2.xy * w1c.xy; a1 += v2.zw * w1c.zw;
            a2 += v2.xy * w2c.xy; a2 += v2.zw * w2c.zw;
            a3 += v2.xy * w3c.xy; a3 += v2.zw * w3c.zw;
            a0 += v3.xy * w0d.xy; a0 += v3.zw * w0d.zw;
            a1 += v3.xy * w1d.xy; a1 += v3.zw * w1d.zw;
            a2 += v3.xy * w2d.xy; a2 += v3.zw * w2d.zw;
            a3 += v3.xy * w3d.xy; a3 += v3.zw * w3d.zw;

            float g0 = (a0.x + a0.y) + vex * we0;
            float g1 = (a1.x + a1.y) + vex * we1;
            float g2 = (a2.x + a2.y) + vex * we2;
            float g3 = (a3.x + a3.y) + vex * we3;

            // quad all-reduce via DPP (every lane ends with the full gate sums)
            g0 += dpp_xor1(g0); g0 += dpp_xor2(g0);
            g1 += dpp_xor1(g1); g1 += dpp_xor2(g1);
            g2 += dpp_xor1(g2); g2 += dpp_xor2(g2);
            g3 += dpp_xor1(g3); g3 += dpp_xor2(g3);

            const float ig = sigm_f(g0 + b0);
            const float fg = sigm_f(g1 + b1);
            const float gg = tanh_f(g2 + b2);
            const float og = sigm_f(g3 + b3);
            c = fg * c + ig * gg;            // identical across the 4 lanes
            const float hnew = og * tanh_f(c);

            if (q == 0) {
                buf[wp][l + 1][j] = hnew;
                if (s - l == TT - 1)
                    hidden_out[((size_t)l * BB + bg) * HH + j] = hnew;
            }
        }

        __syncthreads();
    }
}

// MLP head: hidden [3*512, 33] -> gelu(hidden@W1^T + b1) [.,72] -> @W2^T + b2 [.,18]
__global__ void mlp_head_kernel(const float* __restrict__ hidden,
                                const float* __restrict__ W1, const float* __restrict__ b1,
                                const float* __restrict__ W2, const float* __restrict__ b2,
                                float* __restrict__ out)
{
    const int row = blockIdx.x * blockDim.x + threadIdx.x;   // 0..1535
    if (row >= NL * BB) return;

    float hv[HH];
    #pragma unroll
    for (int k = 0; k < HH; ++k) hv[k] = hidden[row * HH + k];

    float h1[4 * OO];
    #pragma unroll
    for (int m = 0; m < 4 * OO; ++m) {
        float a = b1[m];
        #pragma unroll
        for (int k = 0; k < HH; ++k) a += hv[k] * W1[m * HH + k];
        h1[m] = 0.5f * a * (1.0f + erff(a * 0.70710678118654752f));
    }
    #pragma unroll
    for (int o = 0; o < OO; ++o) {
        float a = b2[o];
        #pragma unroll
        for (int m = 0; m < 4 * OO; ++m) a += h1[m] * W2[o * (4 * OO) + m];
        out[row * OO + o] = a;
    }
}

extern "C" void kernel_launch(void* const* d_in, const int* in_sizes, int n_in,
                              void* d_out, int out_size, void* d_ws, size_t ws_size,
                              hipStream_t stream) {
    const float* x    = (const float*)d_in[0];
    const float* Wih0 = (const float*)d_in[1];
    const float* Whh0 = (const float*)d_in[2];
    const float* bih0 = (const float*)d_in[3];
    const float* bhh0 = (const float*)d_in[4];
    const float* Wih1 = (const float*)d_in[5];
    const float* Whh1 = (const float*)d_in[6];
    const float* bih1 = (const float*)d_in[7];
    const float* bhh1 = (const float*)d_in[8];
    const float* Wih2 = (const float*)d_in[9];
    const float* Whh2 = (const float*)d_in[10];
    const float* bih2 = (const float*)d_in[11];
    const float* bhh2 = (const float*)d_in[12];
    const float* W1   = (const float*)d_in[13];
    const float* b1   = (const float*)d_in[14];
    const float* W2   = (const float*)d_in[15];
    const float* b2   = (const float*)d_in[16];

    float* out    = (float*)d_out;                 // [3,512,18] = 27648 floats
    float* hidden = out + NL * BB * OO;            // [3,512,33] = 50688 floats

    lstm_pipeline_kernel<<<BB, 448, 0, stream>>>(
        x, Wih0, Whh0, bih0, bhh0, Wih1, Whh1, bih1, bhh1,
        Wih2, Whh2, bih2, bhh2, hidden);

    mlp_head_kernel<<<(NL * BB + 255) / 256, 256, 0, stream>>>(
        hidden, W1, b1, W2, b2, out);
}

// Round 5
// 1598.747 us; speedup vs baseline: 2.2918x; 1.1981x over previous
//
#include <hip/hip_runtime.h>
#include <math.h>

// Problem constants (from reference)
#define TT 2048
#define BB 512
#define II 11
#define HH 33
#define NL 3
#define OO 18
#define SLOT 36           // padded vector stride in floats (144 B, 16B-aligned slots)

typedef float f2 __attribute__((ext_vector_type(2)));
typedef float f4 __attribute__((ext_vector_type(4)));

// fast sigmoid / tanh via v_exp_f32 + v_rcp_f32 (saturate correctly at +-inf)
__device__ __forceinline__ float sigm_f(float x) {
    float e = __expf(-x);
    return __builtin_amdgcn_rcpf(1.0f + e);
}
__device__ __forceinline__ float tanh_f(float x) {
    float e = __expf(2.0f * x);
    return 1.0f - 2.0f * __builtin_amdgcn_rcpf(e + 1.0f);
}

// DPP quad_perm [1,0,3,2]: exchange within adjacent lane pairs (VALU pipe, no LDS)
__device__ __forceinline__ float dpp_xor1(float v) {
    return __builtin_bit_cast(float,
        __builtin_amdgcn_update_dpp(0, __builtin_bit_cast(int, v), 0xB1, 0xF, 0xF, true));
}

// guarded 4-float load: element k0+i valid iff k0+i < rem (zero-pad otherwise)
__device__ __forceinline__ f4 gld4(const float* p, int k0, int rem) {
    f4 v;
    v.x = (k0 + 0 < rem) ? p[k0 + 0] : 0.0f;
    v.y = (k0 + 1 < rem) ? p[k0 + 1] : 0.0f;
    v.z = (k0 + 2 < rem) ? p[k0 + 2] : 0.0f;
    v.w = (k0 + 3 < rem) ? p[k0 + 3] : 0.0f;
    return v;
}

// Layer-pipelined LSTM, PAIR-per-unit, role-split columns.
// grid = 512 blocks (one batch element each), block = 256 threads (4 waves).
//   tid < 198 : u = tid>>1 (unit 0..98), p = tid&1 (role).
//               l = u/33, j = u%33.
//   Role p=0 reads the layer INPUT vector (LDS slot l, 36 floats zero-padded) and
//   holds the 4 W_ih gate rows; p=1 reads the OWN-h vector (slot l+1) and holds
//   the 4 W_hh gate rows. Each lane: 4 partial gate dots over its 36 columns
//   (72 pk_fma). Pair all-reduce via 4 DPP adds -> full gate sums in both lanes.
//   Activation dedupe: lane p activates 2 gates using tanh(x)=2*sigm(2x)-1 via
//   branch-free per-lane constants; 2 DPP + 4 cndmask redistribute i,f,g,o.
//   tid 198..208 : x prefetchers (11 features), 2-deep software pipeline.
// LDS: ping-pong buf[2][4][SLOT]; one barrier per superstep.
// __launch_bounds__(256,2): 256-VGPR budget so the 144 weight floats stay in
// true VGPRs (not AGPRs); 2 blocks/CU co-resident hide barrier/LDS latency.
__global__ __launch_bounds__(256, 2) void lstm_pipeline_kernel(
    const float* __restrict__ x,
    const float* __restrict__ Wih0, const float* __restrict__ Whh0,
    const float* __restrict__ bih0, const float* __restrict__ bhh0,
    const float* __restrict__ Wih1, const float* __restrict__ Whh1,
    const float* __restrict__ bih1, const float* __restrict__ bhh1,
    const float* __restrict__ Wih2, const float* __restrict__ Whh2,
    const float* __restrict__ bih2, const float* __restrict__ bhh2,
    float* __restrict__ hidden_out)   // [3, 512, 33]
{
    __shared__ __align__(16) float buf[2][NL + 1][SLOT];

    const int tid = threadIdx.x;
    const int bg  = blockIdx.x;

    for (int i = tid; i < 2 * (NL + 1) * SLOT; i += 256)
        ((float*)buf)[i] = 0.0f;

    const bool comp = (tid < 198);
    const int  u    = tid >> 1;          // unit 0..98
    const int  p    = tid & 1;           // 0 = input-role, 1 = h-role
    const int  l    = (u < 33) ? 0 : (u < 66) ? 1 : 2;
    const int  j    = u - 33 * l;

    const int  pi   = tid - 198;
    const bool pref = (pi >= 0) && (pi < II);
    const float* xrow = x + (size_t)bg * TT * II + (pref ? pi : 0);

    // ---- per-lane weights: 4 gate rows x 36 cols (zero-padded) = 36 named f4 ----
    f4 z4 = {0.0f, 0.0f, 0.0f, 0.0f};
    f4 w00=z4,w01=z4,w02=z4,w03=z4,w04=z4,w05=z4,w06=z4,w07=z4,w08=z4;  // gate i
    f4 w10=z4,w11=z4,w12=z4,w13=z4,w14=z4,w15=z4,w16=z4,w17=z4,w18=z4;  // gate f
    f4 w20=z4,w21=z4,w22=z4,w23=z4,w24=z4,w25=z4,w26=z4,w27=z4,w28=z4;  // gate g
    f4 w30=z4,w31=z4,w32=z4,w33=z4,w34=z4,w35=z4,w36=z4,w37=z4,w38=z4;  // gate o
    float b0 = 0.0f, b1 = 0.0f, b2 = 0.0f, b3 = 0.0f;

    if (comp) {
        const float* bip = (l == 0) ? bih0 : (l == 1) ? bih1 : bih2;
        const float* bhp = (l == 0) ? bhh0 : (l == 1) ? bhh1 : bhh2;
        b0 = bip[0 * HH + j] + bhp[0 * HH + j];
        b1 = bip[1 * HH + j] + bhp[1 * HH + j];
        b2 = bip[2 * HH + j] + bhp[2 * HH + j];
        b3 = bip[3 * HH + j] + bhp[3 * HH + j];

        const float* Wsrc = p ? ((l == 0) ? Whh0 : (l == 1) ? Whh1 : Whh2)
                              : ((l == 0) ? Wih0 : (l == 1) ? Wih1 : Wih2);
        const int kin = (p || l != 0) ? HH : II;
        const float* r0 = Wsrc + (0 * HH + j) * kin;
        const float* r1 = Wsrc + (1 * HH + j) * kin;
        const float* r2 = Wsrc + (2 * HH + j) * kin;
        const float* r3 = Wsrc + (3 * HH + j) * kin;
        w00=gld4(r0,0,kin); w01=gld4(r0,4,kin); w02=gld4(r0,8,kin);
        w03=gld4(r0,12,kin); w04=gld4(r0,16,kin); w05=gld4(r0,20,kin);
        w06=gld4(r0,24,kin); w07=gld4(r0,28,kin); w08=gld4(r0,32,kin);
        w10=gld4(r1,0,kin); w11=gld4(r1,4,kin); w12=gld4(r1,8,kin);
        w13=gld4(r1,12,kin); w14=gld4(r1,16,kin); w15=gld4(r1,20,kin);
        w16=gld4(r1,24,kin); w17=gld4(r1,28,kin); w18=gld4(r1,32,kin);
        w20=gld4(r2,0,kin); w21=gld4(r2,4,kin); w22=gld4(r2,8,kin);
        w23=gld4(r2,12,kin); w24=gld4(r2,16,kin); w25=gld4(r2,20,kin);
        w26=gld4(r2,24,kin); w27=gld4(r2,28,kin); w28=gld4(r2,32,kin);
        w30=gld4(r3,0,kin); w31=gld4(r3,4,kin); w32=gld4(r3,8,kin);
        w33=gld4(r3,12,kin); w34=gld4(r3,16,kin); w35=gld4(r3,20,kin);
        w36=gld4(r3,24,kin); w37=gld4(r3,28,kin); w38=gld4(r3,32,kin);
    }

    __syncthreads();
    float v_next = 0.0f, v_next2 = 0.0f;
    if (pref) {
        buf[0][0][pi] = xrow[0];
        v_next  = xrow[II];
        v_next2 = xrow[2 * II];
    }
    __syncthreads();

    float c = 0.0f;
    const int   vsel = p ? (l + 1) : l;      // which LDS slot this lane reads
    const float mA   = 1.0f + (float)p;      // act-a: 1 -> sigm, 2 -> tanh form
    const float cAc  = -(float)p;

    for (int s = 0; s < TT + NL - 1; ++s) {
        const int rp = s & 1;
        const int wp = rp ^ 1;

        if (pref) {
            if (s + 1 < TT) buf[wp][0][pi] = v_next;     // vmcnt slack: 2 supersteps
            v_next = v_next2;
            if (s + 3 < TT) v_next2 = xrow[(size_t)(s + 3) * II];
        }

        const bool active = comp && (s >= l) && (s - l < TT);
        if (active) {
            const f4* V = (const f4*)(&buf[rp][vsel][0]);
            const f4 v0=V[0], v1=V[1], v2=V[2], v3=V[3], v4=V[4],
                     v5=V[5], v6=V[6], v7=V[7], v8=V[8];

            // 4 partial gate dots over this lane's 36 cols (72 pk_fma, 8 chains)
            f2 A0 = v0.xy*w00.xy, B0 = v0.zw*w00.zw;
            f2 A1 = v0.xy*w10.xy, B1 = v0.zw*w10.zw;
            f2 A2 = v0.xy*w20.xy, B2 = v0.zw*w20.zw;
            f2 A3 = v0.xy*w30.xy, B3 = v0.zw*w30.zw;
            A0 += v1.xy*w01.xy; B0 += v1.zw*w01.zw;
            A1 += v1.xy*w11.xy; B1 += v1.zw*w11.zw;
            A2 += v1.xy*w21.xy; B2 += v1.zw*w21.zw;
            A3 += v1.xy*w31.xy; B3 += v1.zw*w31.zw;
            A0 += v2.xy*w02.xy; B0 += v2.zw*w02.zw;
            A1 += v2.xy*w12.xy; B1 += v2.zw*w12.zw;
            A2 += v2.xy*w22.xy; B2 += v2.zw*w22.zw;
            A3 += v2.xy*w32.xy; B3 += v2.zw*w32.zw;
            A0 += v3.xy*w03.xy; B0 += v3.zw*w03.zw;
            A1 += v3.xy*w13.xy; B1 += v3.zw*w13.zw;
            A2 += v3.xy*w23.xy; B2 += v3.zw*w23.zw;
            A3 += v3.xy*w33.xy; B3 += v3.zw*w33.zw;
            A0 += v4.xy*w04.xy; B0 += v4.zw*w04.zw;
            A1 += v4.xy*w14.xy; B1 += v4.zw*w14.zw;
            A2 += v4.xy*w24.xy; B2 += v4.zw*w24.zw;
            A3 += v4.xy*w34.xy; B3 += v4.zw*w34.zw;
            A0 += v5.xy*w05.xy; B0 += v5.zw*w05.zw;
            A1 += v5.xy*w15.xy; B1 += v5.zw*w15.zw;
            A2 += v5.xy*w25.xy; B2 += v5.zw*w25.zw;
            A3 += v5.xy*w35.xy; B3 += v5.zw*w35.zw;
            A0 += v6.xy*w06.xy; B0 += v6.zw*w06.zw;
            A1 += v6.xy*w16.xy; B1 += v6.zw*w16.zw;
            A2 += v6.xy*w26.xy; B2 += v6.zw*w26.zw;
            A3 += v6.xy*w36.xy; B3 += v6.zw*w36.zw;
            A0 += v7.xy*w07.xy; B0 += v7.zw*w07.zw;
            A1 += v7.xy*w17.xy; B1 += v7.zw*w17.zw;
            A2 += v7.xy*w27.xy; B2 += v7.zw*w27.zw;
            A3 += v7.xy*w37.xy; B3 += v7.zw*w37.zw;
            A0 += v8.xy*w08.xy; B0 += v8.zw*w08.zw;
            A1 += v8.xy*w18.xy; B1 += v8.zw*w18.zw;
            A2 += v8.xy*w28.xy; B2 += v8.zw*w28.zw;
            A3 += v8.xy*w38.xy; B3 += v8.zw*w38.zw;

            float s0 = (A0.x + B0.x) + (A0.y + B0.y);
            float s1 = (A1.x + B1.x) + (A1.y + B1.y);
            float s2 = (A2.x + B2.x) + (A2.y + B2.y);
            float s3 = (A3.x + B3.x) + (A3.y + B3.y);

            // pair all-reduce: full gate sums in both lanes, then bias
            s0 += dpp_xor1(s0); s1 += dpp_xor1(s1);
            s2 += dpp_xor1(s2); s3 += dpp_xor1(s3);
            s0 += b0; s1 += b1; s2 += b2; s3 += b3;

            // activation dedupe: p0 activates gates i,f; p1 activates g,o.
            // tanh(x) = 2*sigm(2x) - 1 -> uniform code via per-lane constants.
            const float aA = p ? s2 : s0;
            const float aB = p ? s3 : s1;
            const float acta = __builtin_fmaf(mA, sigm_f(mA * aA), cAc); // i or g
            const float actb = sigm_f(aB);                               // f or o
            const float xa = dpp_xor1(acta);
            const float xb = dpp_xor1(actb);
            const float ig = p ? xa : acta;
            const float gg = p ? acta : xa;
            const float fg = p ? xb : actb;
            const float og = p ? actb : xb;

            c = __builtin_fmaf(fg, c, ig * gg);   // identical in both lanes
            const float hnew = og * tanh_f(c);

            if (p == 0) {
                buf[wp][l + 1][j] = hnew;
                if (s - l == TT - 1)
                    hidden_out[((size_t)l * BB + bg) * HH + j] = hnew;
            }
        }

        __syncthreads();
    }
}

// MLP head: hidden [3*512, 33] -> gelu(hidden@W1^T + b1) [.,72] -> @W2^T + b2 [.,18]
__global__ void mlp_head_kernel(const float* __restrict__ hidden,
                                const float* __restrict__ W1, const float* __restrict__ b1,
                                const float* __restrict__ W2, const float* __restrict__ b2,
                                float* __restrict__ out)
{
    const int row = blockIdx.x * blockDim.x + threadIdx.x;   // 0..1535
    if (row >= NL * BB) return;

    float hv[HH];
    #pragma unroll
    for (int k = 0; k < HH; ++k) hv[k] = hidden[row * HH + k];

    float h1[4 * OO];
    #pragma unroll
    for (int m = 0; m < 4 * OO; ++m) {
        float a = b1[m];
        #pragma unroll
        for (int k = 0; k < HH; ++k) a += hv[k] * W1[m * HH + k];
        h1[m] = 0.5f * a * (1.0f + erff(a * 0.70710678118654752f));
    }
    #pragma unroll
    for (int o = 0; o < OO; ++o) {
        float a = b2[o];
        #pragma unroll
        for (int m = 0; m < 4 * OO; ++m) a += h1[m] * W2[o * (4 * OO) + m];
        out[row * OO + o] = a;
    }
}

extern "C" void kernel_launch(void* const* d_in, const int* in_sizes, int n_in,
                              void* d_out, int out_size, void* d_ws, size_t ws_size,
                              hipStream_t stream) {
    const float* x    = (const float*)d_in[0];
    const float* Wih0 = (const float*)d_in[1];
    const float* Whh0 = (const float*)d_in[2];
    const float* bih0 = (const float*)d_in[3];
    const float* bhh0 = (const float*)d_in[4];
    const float* Wih1 = (const float*)d_in[5];
    const float* Whh1 = (const float*)d_in[6];
    const float* bih1 = (const float*)d_in[7];
    const float* bhh1 = (const float*)d_in[8];
    const float* Wih2 = (const float*)d_in[9];
    const float* Whh2 = (const float*)d_in[10];
    const float* bih2 = (const float*)d_in[11];
    const float* bhh2 = (const float*)d_in[12];
    const float* W1   = (const float*)d_in[13];
    const float* b1   = (const float*)d_in[14];
    const float* W2   = (const float*)d_in[15];
    const float* b2   = (const float*)d_in[16];

    float* out    = (float*)d_out;                 // [3,512,18] = 27648 floats
    float* hidden = out + NL * BB * OO;            // [3,512,33] = 50688 floats

    lstm_pipeline_kernel<<<BB, 256, 0, stream>>>(
        x, Wih0, Whh0, bih0, bhh0, Wih1, Whh1, bih1, bhh1,
        Wih2, Whh2, bih2, bhh2, hidden);

    mlp_head_kernel<<<(NL * BB + 255) / 256, 256, 0, stream>>>(
        hidden, W1, b1, W2, b2, out);
}

// Round 6
// 1473.756 us; speedup vs baseline: 2.4862x; 1.0848x over previous
//
#include <hip/hip_runtime.h>
#include <math.h>

// Problem constants (from reference)
#define TT 2048
#define BB 512
#define II 11
#define HH 33
#define NL 3
#define OO 18
#define HSLOT 48          // halves per LDS vector slot (96 B, keeps slots 16B-aligned)

typedef _Float16 h2 __attribute__((ext_vector_type(2)));
typedef _Float16 h4 __attribute__((ext_vector_type(4)));
typedef _Float16 h8 __attribute__((ext_vector_type(8)));   // 16 B -> ds_read_b128

// fast sigmoid / tanh via v_exp_f32 + v_rcp_f32 (saturate correctly at +-inf)
__device__ __forceinline__ float sigm_f(float x) {
    float e = __expf(-x);
    return __builtin_amdgcn_rcpf(1.0f + e);
}
__device__ __forceinline__ float tanh_f(float x) {
    float e = __expf(2.0f * x);
    return 1.0f - 2.0f * __builtin_amdgcn_rcpf(e + 1.0f);
}

// DPP quad_perm [1,0,3,2]: exchange within adjacent lane pairs (VALU pipe, no LDS)
__device__ __forceinline__ float dpp_xor1(float v) {
    return __builtin_bit_cast(float,
        __builtin_amdgcn_update_dpp(0, __builtin_bit_cast(int, v), 0xB1, 0xF, 0xF, true));
}

// guarded fp32->fp16 row-slice loads (zero-pad past rem)
__device__ __forceinline__ h8 gldh8(const float* p, int k0, int rem) {
    h8 v;
    #pragma unroll
    for (int i = 0; i < 8; ++i) v[i] = (_Float16)((k0 + i < rem) ? p[k0 + i] : 0.0f);
    return v;
}
__device__ __forceinline__ h4 gldh4(const float* p, int k0, int rem) {
    h4 v;
    #pragma unroll
    for (int i = 0; i < 4; ++i) v[i] = (_Float16)((k0 + i < rem) ? p[k0 + i] : 0.0f);
    return v;
}

// v_dot2_f32_f16 chains: 2 MACs/op, fp32 accumulate
#define D8(a, v, w) do { \
    a = __builtin_amdgcn_fdot2((v).s01, (w).s01, a, false); \
    a = __builtin_amdgcn_fdot2((v).s23, (w).s23, a, false); \
    a = __builtin_amdgcn_fdot2((v).s45, (w).s45, a, false); \
    a = __builtin_amdgcn_fdot2((v).s67, (w).s67, a, false); } while (0)
#define D4(a, v, w) do { \
    a = __builtin_amdgcn_fdot2((v).s01, (w).s01, a, false); \
    a = __builtin_amdgcn_fdot2((v).s23, (w).s23, a, false); } while (0)

// Layer-pipelined LSTM, PAIR-per-unit role-split, fp16 weights/vectors + fdot2.
// grid = 512 blocks (one batch element each), block = 256 threads (4 waves).
//   tid < 198 : u = tid>>1 (unit 0..98), p = tid&1 (role).  l = u/33, j = u%33.
//   Role p=0: reads the layer INPUT vector (slot l) and holds the 4 W_ih gate
//   rows; p=1: reads the OWN-h vector (slot l+1) and holds the 4 W_hh rows.
//   Each lane: 4 partial gate dots over its 36 cols = 72 fdot2 (fp32 acc).
//   Pair all-reduce via 4 DPP adds; activation dedupe via tanh(x)=2*sigm(2x)-1
//   (p0 activates i,f; p1 activates g,o; 2 DPP redistribute).
//   tid 198..208 : x prefetchers (11 features), 2-deep software pipeline.
// fp16 ONLY in weights + LDS staging of x/h; c, biases, activations all fp32.
// LDS: ping-pong buf[2][4][HSLOT] halves; one barrier per superstep.
// __launch_bounds__(256,2): 256-reg slack; ~72 weight + ~40 working VGPRs
// should land as TRUE VGPRs (no AGPR accvgpr_read tax). Occupancy is
// grid-capped at 2 blocks/CU anyway.
__global__ __launch_bounds__(256, 2) void lstm_pipeline_kernel(
    const float* __restrict__ x,
    const float* __restrict__ Wih0, const float* __restrict__ Whh0,
    const float* __restrict__ bih0, const float* __restrict__ bhh0,
    const float* __restrict__ Wih1, const float* __restrict__ Whh1,
    const float* __restrict__ bih1, const float* __restrict__ bhh1,
    const float* __restrict__ Wih2, const float* __restrict__ Whh2,
    const float* __restrict__ bih2, const float* __restrict__ bhh2,
    float* __restrict__ hidden_out)   // [3, 512, 33]
{
    __shared__ __align__(16) _Float16 buf[2][NL + 1][HSLOT];

    const int tid = threadIdx.x;
    const int bg  = blockIdx.x;

    for (int i = tid; i < 2 * (NL + 1) * HSLOT; i += 256)
        ((_Float16*)buf)[i] = (_Float16)0.0f;

    const bool comp = (tid < 198);
    const int  u    = tid >> 1;          // unit 0..98
    const int  p    = tid & 1;           // 0 = input-role, 1 = h-role
    const int  l    = (u < 33) ? 0 : (u < 66) ? 1 : 2;
    const int  j    = u - 33 * l;

    const int  pi   = tid - 198;
    const bool pref = (pi >= 0) && (pi < II);
    const float* xrow = x + (size_t)bg * TT * II + (pref ? pi : 0);

    // ---- per-lane weights: 4 gate rows x 36 cols, packed fp16 = 72 VGPRs ----
    h8 z8 = {0,0,0,0,0,0,0,0};
    h4 z4 = {0,0,0,0};
    h8 w0a=z8,w0b=z8,w0c=z8,w0d=z8; h4 w0t=z4;   // gate i
    h8 w1a=z8,w1b=z8,w1c=z8,w1d=z8; h4 w1t=z4;   // gate f
    h8 w2a=z8,w2b=z8,w2c=z8,w2d=z8; h4 w2t=z4;   // gate g
    h8 w3a=z8,w3b=z8,w3c=z8,w3d=z8; h4 w3t=z4;   // gate o
    float b0 = 0.0f, b1 = 0.0f, b2 = 0.0f, b3 = 0.0f;

    if (comp) {
        const float* bip = (l == 0) ? bih0 : (l == 1) ? bih1 : bih2;
        const float* bhp = (l == 0) ? bhh0 : (l == 1) ? bhh1 : bhh2;
        // bias only on the p=0 lane; pair all-reduce restores it for both
        if (p == 0) {
            b0 = bip[0 * HH + j] + bhp[0 * HH + j];
            b1 = bip[1 * HH + j] + bhp[1 * HH + j];
            b2 = bip[2 * HH + j] + bhp[2 * HH + j];
            b3 = bip[3 * HH + j] + bhp[3 * HH + j];
        }

        const float* Wsrc = p ? ((l == 0) ? Whh0 : (l == 1) ? Whh1 : Whh2)
                              : ((l == 0) ? Wih0 : (l == 1) ? Wih1 : Wih2);
        const int kin = (p || l != 0) ? HH : II;
        const float* r0 = Wsrc + (0 * HH + j) * kin;
        const float* r1 = Wsrc + (1 * HH + j) * kin;
        const float* r2 = Wsrc + (2 * HH + j) * kin;
        const float* r3 = Wsrc + (3 * HH + j) * kin;
        w0a = gldh8(r0, 0, kin); w0b = gldh8(r0, 8, kin);
        w0c = gldh8(r0, 16, kin); w0d = gldh8(r0, 24, kin); w0t = gldh4(r0, 32, kin);
        w1a = gldh8(r1, 0, kin); w1b = gldh8(r1, 8, kin);
        w1c = gldh8(r1, 16, kin); w1d = gldh8(r1, 24, kin); w1t = gldh4(r1, 32, kin);
        w2a = gldh8(r2, 0, kin); w2b = gldh8(r2, 8, kin);
        w2c = gldh8(r2, 16, kin); w2d = gldh8(r2, 24, kin); w2t = gldh4(r2, 32, kin);
        w3a = gldh8(r3, 0, kin); w3b = gldh8(r3, 8, kin);
        w3c = gldh8(r3, 16, kin); w3d = gldh8(r3, 24, kin); w3t = gldh4(r3, 32, kin);
    }

    __syncthreads();
    float v_next = 0.0f, v_next2 = 0.0f;
    if (pref) {
        buf[0][0][pi] = (_Float16)xrow[0];
        v_next  = xrow[II];
        v_next2 = xrow[2 * II];
    }
    __syncthreads();

    float c = 0.0f;
    const int   vsel = p ? (l + 1) : l;      // which LDS slot this lane reads
    const float mA   = 1.0f + (float)p;      // activation-a: 1 -> sigm, 2 -> tanh
    const float cAc  = -(float)p;

    for (int s = 0; s < TT + NL - 1; ++s) {
        const int rp = s & 1;
        const int wp = rp ^ 1;

        if (pref) {
            if (s + 1 < TT) buf[wp][0][pi] = (_Float16)v_next;  // vmcnt slack: 2 steps
            v_next = v_next2;
            if (s + 3 < TT) v_next2 = xrow[(size_t)(s + 3) * II];
        }

        const bool active = comp && (s >= l) && (s - l < TT);
        if (active) {
            // this lane's 36-half vector: 4 x ds_read_b128 + 1 x ds_read_b64
            const h8* V = (const h8*)(&buf[rp][vsel][0]);
            const h8 v0 = V[0], v1 = V[1], v2 = V[2], v3 = V[3];
            const h4 vt = *(const h4*)(&buf[rp][vsel][32]);

            // 4 partial gate dots: 72 v_dot2_f32_f16, fp32 accumulate
            float a0 = b0, a1 = b1, a2 = b2, a3 = b3;
            D8(a0, v0, w0a); D8(a1, v0, w1a); D8(a2, v0, w2a); D8(a3, v0, w3a);
            D8(a0, v1, w0b); D8(a1, v1, w1b); D8(a2, v1, w2b); D8(a3, v1, w3b);
            D8(a0, v2, w0c); D8(a1, v2, w1c); D8(a2, v2, w2c); D8(a3, v2, w3c);
            D8(a0, v3, w0d); D8(a1, v3, w1d); D8(a2, v3, w2d); D8(a3, v3, w3d);
            D4(a0, vt, w0t); D4(a1, vt, w1t); D4(a2, vt, w2t); D4(a3, vt, w3t);

            // pair all-reduce: full gate pre-activations in both lanes
            a0 += dpp_xor1(a0); a1 += dpp_xor1(a1);
            a2 += dpp_xor1(a2); a3 += dpp_xor1(a3);

            // activation dedupe: p0 activates i,f; p1 activates g,o
            // tanh(x) = 2*sigm(2x) - 1 via per-lane constants (branch-free)
            const float aA = p ? a2 : a0;
            const float aB = p ? a3 : a1;
            const float acta = __builtin_fmaf(mA, sigm_f(mA * aA), cAc); // i or g
            const float actb = sigm_f(aB);                               // f or o
            const float xa = dpp_xor1(acta);
            const float xb = dpp_xor1(actb);
            const float ig = p ? xa : acta;
            const float gg = p ? acta : xa;
            const float fg = p ? xb : actb;
            const float og = p ? actb : xb;

            c = __builtin_fmaf(fg, c, ig * gg);   // identical in both lanes (fp32)
            const float hnew = og * tanh_f(c);

            if (p == 0) {
                buf[wp][l + 1][j] = (_Float16)hnew;
                if (s - l == TT - 1)
                    hidden_out[((size_t)l * BB + bg) * HH + j] = hnew;
            }
        }

        __syncthreads();
    }
}

// MLP head: hidden [3*512, 33] -> gelu(hidden@W1^T + b1) [.,72] -> @W2^T + b2 [.,18]
// (fp32 throughout; 1536 rows, negligible runtime)
__global__ void mlp_head_kernel(const float* __restrict__ hidden,
                                const float* __restrict__ W1, const float* __restrict__ b1,
                                const float* __restrict__ W2, const float* __restrict__ b2,
                                float* __restrict__ out)
{
    const int row = blockIdx.x * blockDim.x + threadIdx.x;   // 0..1535
    if (row >= NL * BB) return;

    float hv[HH];
    #pragma unroll
    for (int k = 0; k < HH; ++k) hv[k] = hidden[row * HH + k];

    float h1[4 * OO];
    #pragma unroll
    for (int m = 0; m < 4 * OO; ++m) {
        float a = b1[m];
        #pragma unroll
        for (int k = 0; k < HH; ++k) a += hv[k] * W1[m * HH + k];
        h1[m] = 0.5f * a * (1.0f + erff(a * 0.70710678118654752f));
    }
    #pragma unroll
    for (int o = 0; o < OO; ++o) {
        float a = b2[o];
        #pragma unroll
        for (int m = 0; m < 4 * OO; ++m) a += h1[m] * W2[o * (4 * OO) + m];
        out[row * OO + o] = a;
    }
}

extern "C" void kernel_launch(void* const* d_in, const int* in_sizes, int n_in,
                              void* d_out, int out_size, void* d_ws, size_t ws_size,
                              hipStream_t stream) {
    const float* x    = (const float*)d_in[0];
    const float* Wih0 = (const float*)d_in[1];
    const float* Whh0 = (const float*)d_in[2];
    const float* bih0 = (const float*)d_in[3];
    const float* bhh0 = (const float*)d_in[4];
    const float* Wih1 = (const float*)d_in[5];
    const float* Whh1 = (const float*)d_in[6];
    const float* bih1 = (const float*)d_in[7];
    const float* bhh1 = (const float*)d_in[8];
    const float* Wih2 = (const float*)d_in[9];
    const float* Whh2 = (const float*)d_in[10];
    const float* bih2 = (const float*)d_in[11];
    const float* bhh2 = (const float*)d_in[12];
    const float* W1   = (const float*)d_in[13];
    const float* b1   = (const float*)d_in[14];
    const float* W2   = (const float*)d_in[15];
    const float* b2   = (const float*)d_in[16];

    float* out    = (float*)d_out;                 // [3,512,18] = 27648 floats
    float* hidden = out + NL * BB * OO;            // [3,512,33] = 50688 floats

    lstm_pipeline_kernel<<<BB, 256, 0, stream>>>(
        x, Wih0, Whh0, bih0, bhh0, Wih1, Whh1, bih1, bhh1,
        Wih2, Whh2, bih2, bhh2, hidden);

    mlp_head_kernel<<<(NL * BB + 255) / 256, 256, 0, stream>>>(
        hidden, W1, b1, W2, b2, out);
}